// Round 11
// baseline (1900.706 us; speedup 1.0000x reference)
//
#include <hip/hip_runtime.h>

typedef __attribute__((ext_vector_type(4))) int i32x4;
typedef __attribute__((ext_vector_type(16))) int i32x16;

#define K_ELEMS 4096
#define N_DIM 4096
#define BM 256
#define BN 256
#define BKB 64             // K-bytes per tile row (i8: 64 elems) -> LDS 64KB, 2 blocks/CU
#define NT (K_ELEMS / BKB) // 64 K-tiles
#define HALF (128 * BKB)   // bytes per half-tile region (8192)
#define BOFF (BM * BKB)    // B region offset within a buffer (16384 bytes)

// ---------- helpers ----------

__device__ __forceinline__ void gload16(const signed char* g, signed char* l) {
  __builtin_amdgcn_global_load_lds(
      (const __attribute__((address_space(1))) void*)g,
      (__attribute__((address_space(3))) void*)l,
      16, 0, 0);
}

// swizzle v3 for 64B rows (4 x 16B slots): slot ^= ((row>>1)&3) ^ ((row>>3)&3).
// Start positions (row&1)*16 + slot'*4 span 8 uniform x4-aligned banks, 8
// lanes each — same profile R9 measured as ZERO conflicts at 128B rows.
__device__ __forceinline__ i32x4 ldfrag_(const signed char* p, int row, int c16) {
  int o = row * BKB + ((c16 ^ (((row >> 1) & 3) ^ ((row >> 3) & 3))) << 4);
  return *reinterpret_cast<const i32x4*>(p + o);
}

// ---------- fused prep: rows [0,Mdim) = prune+quant x; [Mdim,Mdim+Ndim) = quant w ----------

__global__ void __launch_bounds__(256) quant_all(const float* __restrict__ x,
                                                 const float* __restrict__ w,
                                                 signed char* __restrict__ xq,
                                                 signed char* __restrict__ wq,
                                                 float* __restrict__ sx,
                                                 float* __restrict__ sw, int Mdim) {
  const int blk = blockIdx.x;
  const bool isX = blk < Mdim;
  const int row = isX ? blk : blk - Mdim;
  const float* in = isX ? x : w;
  signed char* q = isX ? xq : wq;
  float* sc = isX ? sx : sw;

  const float4* rf = reinterpret_cast<const float4*>(in + (size_t)row * K_ELEMS);
  float4 vals[4];
  float m = 0.f;
#pragma unroll
  for (int i = 0; i < 4; ++i) {
    float4 v = rf[threadIdx.x + i * 256];   // one float4 == one 2:4 group
    if (isX) {
      float vv[4] = {v.x, v.y, v.z, v.w};
      float av[4] = {fabsf(v.x), fabsf(v.y), fabsf(v.z), fabsf(v.w)};
      float o[4];
#pragma unroll
      for (int e = 0; e < 4; ++e) {
        int beats = 0;
#pragma unroll
        for (int j = 0; j < 4; ++j) {
          if (j == e) continue;
          beats += (av[j] > av[e] || (av[j] == av[e] && j < e)) ? 1 : 0;
        }
        o[e] = (beats < 2) ? vv[e] : 0.0f;
      }
      v.x = o[0]; v.y = o[1]; v.z = o[2]; v.w = o[3];
    }
    vals[i] = v;
    m = fmaxf(m, fmaxf(fmaxf(fabsf(v.x), fabsf(v.y)), fmaxf(fabsf(v.z), fabsf(v.w))));
  }
#pragma unroll
  for (int off = 32; off; off >>= 1) m = fmaxf(m, __shfl_xor(m, off));
  __shared__ float red[4];
  if ((threadIdx.x & 63) == 0) red[threadIdx.x >> 6] = m;
  __syncthreads();
  const float rm = fmaxf(fmaxf(red[0], red[1]), fmaxf(red[2], red[3]));
  const float inv = rm > 0.f ? 127.0f / rm : 0.f;
  if (threadIdx.x == 0) sc[row] = rm * (1.0f / 127.0f);
  int* qo = reinterpret_cast<int*>(q + (size_t)row * K_ELEMS);
#pragma unroll
  for (int i = 0; i < 4; ++i) {
    int q0 = __float2int_rn(vals[i].x * inv);
    int q1 = __float2int_rn(vals[i].y * inv);
    int q2 = __float2int_rn(vals[i].z * inv);
    int q3 = __float2int_rn(vals[i].w * inv);
    qo[threadIdx.x + i * 256] = (q0 & 255) | ((q1 & 255) << 8) | ((q2 & 255) << 16) | (q3 << 24);
  }
}

// ---------- 256x256 i8 GEMM: R10 skeleton, BKB=64 -> 64KB LDS, 2 blocks/CU ----------
// Per phase per wave: 4 MFMA (2m x 2ks); reads P1=6, P2=2, P3=4, P4=0.
// Staging: 512 x 16B chunks per half-tile, 1 chunk/thread; vmcnt(1) tail.

#define LD_A32(LP, MH)                                                      \
  _Pragma("unroll") for (int m_ = 0; m_ < 2; ++m_)                          \
  _Pragma("unroll") for (int ks_ = 0; ks_ < 2; ++ks_)                       \
    a[m_][ks_] = ldfrag_((LP), wrow0 + (MH)*64 + m_*32 + r32, ks_*2 + kh);

#define LD_B32(LP, NH, BV)                                                  \
  _Pragma("unroll") for (int ks_ = 0; ks_ < 2; ++ks_)                       \
    BV[ks_] = ldfrag_((LP) + BOFF, wcol0 + (NH)*32 + r32, ks_*2 + kh);

#define QUAD32(MH, NH, BV)                                                  \
  _Pragma("unroll") for (int m_ = 0; m_ < 2; ++m_)                          \
  _Pragma("unroll") for (int ks_ = 0; ks_ < 2; ++ks_)                       \
    acc[(MH)*2 + m_][NH] = __builtin_amdgcn_mfma_i32_32x32x32_i8(            \
        a[m_][ks_], BV[ks_], acc[(MH)*2 + m_][NH], 0, 0, 0);

#define STG(G, O, LP, KK) gload16((G) + (O) + (KK), (LP) + l0)

__global__ void __launch_bounds__(512, 4) gemm256(const signed char* __restrict__ A,
                                                  const signed char* __restrict__ B,
                                                  const float* __restrict__ sx,
                                                  const float* __restrict__ sw,
                                                  float* __restrict__ C) {
  __shared__ signed char lds[2][2 * BM * BKB];  // [buf][ A(16384) | B(16384) ] = 64KB

  const int nbn = N_DIM / BN;                 // 16
  const int cpx = gridDim.x >> 3;             // grid % 8 == 0 (bijective XCD swizzle)
  const int bid = blockIdx.x;
  const int swz = (bid & 7) * cpx + (bid >> 3);
  const int bm = swz / nbn, bn = swz % nbn;

  const int tid = threadIdx.x;
  const int lane = tid & 63;
  const int wid = tid >> 6;
  const int wr = wid >> 2;                    // 0..1: M half
  const int wc = wid & 3;                     // 0..3: N quarter
  const int r32 = lane & 31;
  const int kh = lane >> 5;                   // k 16-byte half 0..1
  const int wrow0 = wr * 128;
  const int wcol0 = wc * 64;

  // staging: 512 x 16B chunks per half-tile; thread covers chunk tid (<512... tid<512 all).
  // linear LDS dest; inverse-swizzled global source (same involution as read):
  // s = c ^ ((c>>3)&3) ^ ((c>>5)&3)   (row = c>>2 untouched; flips slot bits 0-1)
  const int c0 = tid;
  const int s0 = c0 ^ ((c0 >> 3) & 3) ^ ((c0 >> 5) & 3);
  const int l0 = c0 * 16;                     // lds byte offset within half
  const size_t aRow = (size_t)bm * BM, bRow = (size_t)bn * BN;
  const size_t gA0 = (aRow +       (s0 >> 2)) * K_ELEMS + (s0 & 3) * 16;
  const size_t gA1 = (aRow + 128 + (s0 >> 2)) * K_ELEMS + (s0 & 3) * 16;
  const size_t gB0 = (bRow +       (s0 >> 2)) * K_ELEMS + (s0 & 3) * 16;
  const size_t gB1 = (bRow + 128 + (s0 >> 2)) * K_ELEMS + (s0 & 3) * 16;

  i32x4 a[2][2], b0[2], b1[2];
  i32x16 acc[4][2] = {};

  // prologue (R2-pattern, 1-load STGs): tile0 full + tile1 A-h0; vmcnt(1)
  STG(A, gA0, &lds[0][0], 0);
  STG(A, gA1, &lds[0][HALF], 0);
  STG(B, gB0, &lds[0][BOFF], 0);
  STG(B, gB1, &lds[0][BOFF + HALF], 0);
  STG(A, gA0, &lds[1][0], BKB);
  asm volatile("s_waitcnt vmcnt(1)" ::: "memory");
  __builtin_amdgcn_s_barrier();

  for (int t = 0; t < NT; ++t) {
    signed char* Lc = lds[t & 1];
    signed char* Ln = lds[(t & 1) ^ 1];
    const int k1 = ((t + 1) & (NT - 1)) * BKB;  // tail wrap: redundant, harmless
    const int k2 = ((t + 2) & (NT - 1)) * BKB;

    // P1: A[mh0] + B[nh0] reads (6); stage A-h1(t+1); quadrant (0,0)
    LD_A32(Lc, 0);
    LD_B32(Lc, 0, b0);
    STG(A, gA1, Ln + HALF, k1);
    __builtin_amdgcn_s_barrier();
    asm volatile("s_waitcnt lgkmcnt(0)" ::: "memory");
    __builtin_amdgcn_s_setprio(1);
    QUAD32(0, 0, b0);
    __builtin_amdgcn_s_setprio(0);
    __builtin_amdgcn_s_barrier();

    // P2: B[nh1] reads (2); stage B-h0(t+1); quadrant (0,1)
    LD_B32(Lc, 1, b1);
    STG(B, gB0, Ln + BOFF, k1);
    __builtin_amdgcn_s_barrier();
    asm volatile("s_waitcnt lgkmcnt(0)" ::: "memory");
    __builtin_amdgcn_s_setprio(1);
    QUAD32(0, 1, b1);
    __builtin_amdgcn_s_setprio(0);
    __builtin_amdgcn_s_barrier();

    // P3: A[mh1] reads (4); stage B-h1(t+1); quadrant (1,1)
    LD_A32(Lc, 1);
    STG(B, gB1, Ln + BOFF + HALF, k1);
    __builtin_amdgcn_s_barrier();
    asm volatile("s_waitcnt lgkmcnt(0)" ::: "memory");
    __builtin_amdgcn_s_setprio(1);
    QUAD32(1, 1, b1);
    __builtin_amdgcn_s_setprio(0);
    __builtin_amdgcn_s_barrier();

    // P4: no ds_reads (b0 live from P1); stage A-h0(t+2); quadrant (1,0);
    //     vmcnt(1): A1,B0,B1(t+1) resident, A0(t+2)'s load stays in flight
    STG(A, gA0, Lc, k2);
    __builtin_amdgcn_s_barrier();
    __builtin_amdgcn_s_setprio(1);
    QUAD32(1, 0, b0);
    __builtin_amdgcn_s_setprio(0);
    asm volatile("s_waitcnt vmcnt(1)" ::: "memory");
    __builtin_amdgcn_s_barrier();
  }

  // epilogue: dequant out = acc * sx[row] * sw[col]
  // C/D layout: col=lane&31, row=(reg&3)+8*(reg>>2)+4*(lane>>5)
  const int rb = bm * BM + wrow0;
  const int cb = bn * BN + wcol0 + r32;
#pragma unroll
  for (int mi = 0; mi < 4; ++mi)
#pragma unroll
    for (int ni = 0; ni < 2; ++ni) {
      const int col = cb + ni * 32;
      const float swc = sw[col];
#pragma unroll
      for (int reg = 0; reg < 16; ++reg) {
        const int row = rb + mi * 32 + (reg & 3) + 8 * (reg >> 2) + 4 * kh;
        C[(size_t)row * N_DIM + col] = (float)acc[mi][ni][reg] * sx[row] * swc;
      }
    }
}

// ---------- launch ----------

extern "C" void kernel_launch(void* const* d_in, const int* in_sizes, int n_in,
                              void* d_out, int out_size, void* d_ws, size_t ws_size,
                              hipStream_t stream) {
  const float* x = (const float*)d_in[0];
  const float* w = (const float*)d_in[1];
  float* out = (float*)d_out;

  const int Mdim = in_sizes[0] / K_ELEMS;      // 8192
  const int Ndim = in_sizes[1] / K_ELEMS;      // 4096

  signed char* xq = (signed char*)d_ws;                          // 32 MB
  signed char* wq = xq + (size_t)Mdim * K_ELEMS;                 // 16 MB
  float* sx = (float*)(wq + (size_t)Ndim * K_ELEMS);             // 32 KB
  float* sw = sx + Mdim;                                         // 16 KB

  quant_all<<<Mdim + Ndim, 256, 0, stream>>>(x, w, xq, wq, sx, sw, Mdim);

  const int grid = (Mdim / BM) * (N_DIM / BN);                   // 32 * 16 = 512
  gemm256<<<grid, 512, 0, stream>>>(xq, wq, sx, sw, out);
}

// Round 12
// 219.452 us; speedup vs baseline: 8.6612x; 8.6612x over previous
//
#include <hip/hip_runtime.h>

typedef __attribute__((ext_vector_type(4))) int i32x4;
typedef __attribute__((ext_vector_type(16))) int i32x16;

#define K_ELEMS 4096
#define N_DIM 4096
#define BM 128
#define BN 128
#define BKB 128            // K-bytes per tile row (i8) — same 128B row geometry as R10
#define NT (K_ELEMS / BKB) // 32 K-tiles
#define HALF (64 * BKB)    // bytes per half-panel region (8192 = 64 rows)
#define BOFF (BM * BKB)    // B region offset within a buffer (16384 bytes)

// ---------- helpers ----------

__device__ __forceinline__ void gload16(const signed char* g, signed char* l) {
  __builtin_amdgcn_global_load_lds(
      (const __attribute__((address_space(1))) void*)g,
      (__attribute__((address_space(3))) void*)l,
      16, 0, 0);
}

// swizzle v2 (R9/R10-validated: ZERO conflicts with this exact read pattern):
// 16B-slot index ^= (row&7) ^ ((row>>3)&3), rows are 128B (8 slots)
__device__ __forceinline__ i32x4 ldfrag_(const signed char* p, int row, int c16) {
  int o = row * BKB + ((c16 ^ ((row & 7) ^ ((row >> 3) & 3))) << 4);
  return *reinterpret_cast<const i32x4*>(p + o);
}

// ---------- prep (R10 verbatim, proven): prune x + per-row i8 quantize ----------

template <bool PRUNE>
__global__ void __launch_bounds__(256) quant_rows(const float* __restrict__ in,
                                                  signed char* __restrict__ q,
                                                  float* __restrict__ scale) {
  const int row = blockIdx.x;
  const float4* rf = reinterpret_cast<const float4*>(in + (size_t)row * K_ELEMS);
  float4 vals[4];
  float m = 0.f;
#pragma unroll
  for (int i = 0; i < 4; ++i) {
    float4 v = rf[threadIdx.x + i * 256];   // one float4 == one 2:4 group
    if (PRUNE) {
      float vv[4] = {v.x, v.y, v.z, v.w};
      float av[4] = {fabsf(v.x), fabsf(v.y), fabsf(v.z), fabsf(v.w)};
      float o[4];
#pragma unroll
      for (int e = 0; e < 4; ++e) {
        int beats = 0;
#pragma unroll
        for (int j = 0; j < 4; ++j) {
          if (j == e) continue;
          beats += (av[j] > av[e] || (av[j] == av[e] && j < e)) ? 1 : 0;
        }
        o[e] = (beats < 2) ? vv[e] : 0.0f;
      }
      v.x = o[0]; v.y = o[1]; v.z = o[2]; v.w = o[3];
    }
    vals[i] = v;
    m = fmaxf(m, fmaxf(fmaxf(fabsf(v.x), fabsf(v.y)), fmaxf(fabsf(v.z), fabsf(v.w))));
  }
#pragma unroll
  for (int off = 32; off; off >>= 1) m = fmaxf(m, __shfl_xor(m, off));
  __shared__ float red[4];
  if ((threadIdx.x & 63) == 0) red[threadIdx.x >> 6] = m;
  __syncthreads();
  const float rm = fmaxf(fmaxf(red[0], red[1]), fmaxf(red[2], red[3]));
  const float inv = rm > 0.f ? 127.0f / rm : 0.f;
  if (threadIdx.x == 0) scale[row] = rm * (1.0f / 127.0f);
  int* qo = reinterpret_cast<int*>(q + (size_t)row * K_ELEMS);
#pragma unroll
  for (int i = 0; i < 4; ++i) {
    int q0 = __float2int_rn(vals[i].x * inv);
    int q1 = __float2int_rn(vals[i].y * inv);
    int q2 = __float2int_rn(vals[i].z * inv);
    int q3 = __float2int_rn(vals[i].w * inv);
    qo[threadIdx.x + i * 256] = (q0 & 255) | ((q1 & 255) << 8) | ((q2 & 255) << 16) | (q3 << 24);
  }
}

// ---------- 128x128 i8 GEMM, 4 waves, 64KB LDS -> 2 independent blocks/CU ----------
// R10 micro-structure verbatim (4-phase R2 skeleton, swizzle v2, vmcnt(2),
// b0/b1 register reuse, verified C/D layout), rescaled: per wave 64x64 output
// (acc[2][2] i32x16 = 64 AGPR; ~144 total regs fits 256-budget at 2 waves/EU).

#define LD_A32(LP, MH)                                                      \
  _Pragma("unroll") for (int ks_ = 0; ks_ < 4; ++ks_)                       \
    a[ks_] = ldfrag_((LP), wrow0 + (MH)*32 + r32, ks_*2 + kh);

#define LD_B32(LP, NH, BV)                                                  \
  _Pragma("unroll") for (int ks_ = 0; ks_ < 4; ++ks_)                       \
    BV[ks_] = ldfrag_((LP) + BOFF, wcol0 + (NH)*32 + r32, ks_*2 + kh);

#define QUAD32(MH, NH, BV)                                                  \
  _Pragma("unroll") for (int ks_ = 0; ks_ < 4; ++ks_)                       \
    acc[MH][NH] = __builtin_amdgcn_mfma_i32_32x32x32_i8(                     \
        a[ks_], BV[ks_], acc[MH][NH], 0, 0, 0);

#define STG(G, O0, O1, LP, KK)                                              \
  do { gload16((G) + (O0) + (KK), (LP) + l0);                               \
       gload16((G) + (O1) + (KK), (LP) + l1); } while (0)

__global__ void __launch_bounds__(256, 2) gemm128(const signed char* __restrict__ A,
                                                  const signed char* __restrict__ B,
                                                  const float* __restrict__ sx,
                                                  const float* __restrict__ sw,
                                                  float* __restrict__ C) {
  __shared__ signed char lds[2][2 * BM * BKB];  // [buf][ A(16384) | B(16384) ] = 64KB

  const int nbn = N_DIM / BN;                 // 32
  const int cpx = gridDim.x >> 3;             // grid % 8 == 0 (bijective XCD swizzle)
  const int bid = blockIdx.x;
  const int swz = (bid & 7) * cpx + (bid >> 3);
  const int bm = swz / nbn, bn = swz % nbn;

  const int tid = threadIdx.x;
  const int lane = tid & 63;
  const int wid = tid >> 6;                   // 0..3
  const int wr = wid >> 1;                    // 0..1: M half (rows wr*64..)
  const int wc = wid & 1;                     // 0..1: N half (cols wc*64..)
  const int r32 = lane & 31;
  const int kh = lane >> 5;                   // k 16-byte half 0..1
  const int wrow0 = wr * 64;
  const int wcol0 = wc * 64;

  // staging: 512 x 16B chunks per half-panel (row=c>>3, slot=c&7); thread
  // covers chunks tid, tid+256. Linear LDS dest; inverse-swizzled global
  // source (same involution as read): s = c ^ ((c>>3)&7) ^ ((c>>6)&3)
  const int c0 = tid, c1 = tid + 256;
  const int s0 = c0 ^ ((c0 >> 3) & 7) ^ ((c0 >> 6) & 3);
  const int s1 = c1 ^ ((c1 >> 3) & 7) ^ ((c1 >> 6) & 3);
  const int l0 = c0 * 16, l1 = c1 * 16;       // lds byte offsets within half
  const size_t aRow = (size_t)bm * BM, bRow = (size_t)bn * BN;
  const size_t gA00 = (aRow +      (s0 >> 3)) * K_ELEMS + (s0 & 7) * 16;
  const size_t gA01 = (aRow +      (s1 >> 3)) * K_ELEMS + (s1 & 7) * 16;
  const size_t gA10 = (aRow + 64 + (s0 >> 3)) * K_ELEMS + (s0 & 7) * 16;
  const size_t gA11 = (aRow + 64 + (s1 >> 3)) * K_ELEMS + (s1 & 7) * 16;
  const size_t gB00 = (bRow +      (s0 >> 3)) * K_ELEMS + (s0 & 7) * 16;
  const size_t gB01 = (bRow +      (s1 >> 3)) * K_ELEMS + (s1 & 7) * 16;
  const size_t gB10 = (bRow + 64 + (s0 >> 3)) * K_ELEMS + (s0 & 7) * 16;
  const size_t gB11 = (bRow + 64 + (s1 >> 3)) * K_ELEMS + (s1 & 7) * 16;

  i32x4 a[4], b0[4], b1[4];
  i32x16 acc[2][2] = {};

  // prologue (R2 pattern): tile0 full + tile1 A-h0; vmcnt(2)
  STG(A, gA00, gA01, &lds[0][0], 0);
  STG(A, gA10, gA11, &lds[0][HALF], 0);
  STG(B, gB00, gB01, &lds[0][BOFF], 0);
  STG(B, gB10, gB11, &lds[0][BOFF + HALF], 0);
  STG(A, gA00, gA01, &lds[1][0], BKB);
  asm volatile("s_waitcnt vmcnt(2)" ::: "memory");
  __builtin_amdgcn_s_barrier();

  for (int t = 0; t < NT; ++t) {
    signed char* Lc = lds[t & 1];
    signed char* Ln = lds[(t & 1) ^ 1];
    const int k1 = ((t + 1) & (NT - 1)) * BKB;  // tail wrap: redundant, harmless
    const int k2 = ((t + 2) & (NT - 1)) * BKB;

    // P1: A[mh0] + B[nh0] reads (8); stage A-h1(t+1); quadrant (0,0)
    LD_A32(Lc, 0);
    LD_B32(Lc, 0, b0);
    STG(A, gA10, gA11, Ln + HALF, k1);
    __builtin_amdgcn_s_barrier();
    asm volatile("s_waitcnt lgkmcnt(0)" ::: "memory");
    __builtin_amdgcn_s_setprio(1);
    QUAD32(0, 0, b0);
    __builtin_amdgcn_s_setprio(0);
    __builtin_amdgcn_s_barrier();

    // P2: B[nh1] reads (4); stage B-h0(t+1); quadrant (0,1)
    LD_B32(Lc, 1, b1);
    STG(B, gB00, gB01, Ln + BOFF, k1);
    __builtin_amdgcn_s_barrier();
    asm volatile("s_waitcnt lgkmcnt(0)" ::: "memory");
    __builtin_amdgcn_s_setprio(1);
    QUAD32(0, 1, b1);
    __builtin_amdgcn_s_setprio(0);
    __builtin_amdgcn_s_barrier();

    // P3: A[mh1] reads (4); stage B-h1(t+1); quadrant (1,1)
    LD_A32(Lc, 1);
    STG(B, gB10, gB11, Ln + BOFF + HALF, k1);
    __builtin_amdgcn_s_barrier();
    asm volatile("s_waitcnt lgkmcnt(0)" ::: "memory");
    __builtin_amdgcn_s_setprio(1);
    QUAD32(1, 1, b1);
    __builtin_amdgcn_s_setprio(0);
    __builtin_amdgcn_s_barrier();

    // P4: no ds_reads (b0 live from P1); stage A-h0(t+2); quadrant (1,0);
    //     vmcnt(2): A-h1,B(t+1) resident, A-h0(t+2)'s 2 loads stay in flight
    STG(A, gA00, gA01, Lc, k2);
    __builtin_amdgcn_s_barrier();
    __builtin_amdgcn_s_setprio(1);
    QUAD32(1, 0, b0);
    __builtin_amdgcn_s_setprio(0);
    asm volatile("s_waitcnt vmcnt(2)" ::: "memory");
    __builtin_amdgcn_s_barrier();
  }

  // epilogue: dequant out = acc * sx[row] * sw[col]
  // C/D layout: col=lane&31, row=(reg&3)+8*(reg>>2)+4*(lane>>5)
  const int rb = bm * BM + wrow0;
  const int cb = bn * BN + wcol0 + r32;
#pragma unroll
  for (int mi = 0; mi < 2; ++mi)
#pragma unroll
    for (int ni = 0; ni < 2; ++ni) {
      const int col = cb + ni * 32;
      const float swc = sw[col];
#pragma unroll
      for (int reg = 0; reg < 16; ++reg) {
        const int row = rb + mi * 32 + (reg & 3) + 8 * (reg >> 2) + 4 * kh;
        C[(size_t)row * N_DIM + col] = (float)acc[mi][ni][reg] * sx[row] * swc;
      }
    }
}

// ---------- launch ----------

extern "C" void kernel_launch(void* const* d_in, const int* in_sizes, int n_in,
                              void* d_out, int out_size, void* d_ws, size_t ws_size,
                              hipStream_t stream) {
  const float* x = (const float*)d_in[0];
  const float* w = (const float*)d_in[1];
  float* out = (float*)d_out;

  const int Mdim = in_sizes[0] / K_ELEMS;      // 8192
  const int Ndim = in_sizes[1] / K_ELEMS;      // 4096

  signed char* xq = (signed char*)d_ws;                          // 32 MB
  signed char* wq = xq + (size_t)Mdim * K_ELEMS;                 // 16 MB
  float* sx = (float*)(wq + (size_t)Ndim * K_ELEMS);             // 32 KB
  float* sw = sx + Mdim;                                         // 16 KB

  quant_rows<true><<<Mdim, 256, 0, stream>>>(x, xq, sx);
  quant_rows<false><<<Ndim, 256, 0, stream>>>(w, wq, sw);

  const int grid = (Mdim / BM) * (N_DIM / BN);                   // 64 * 32 = 2048
  gemm128<<<grid, 256, 0, stream>>>(xq, wq, sx, sw, out);
}

// Round 13
// 199.559 us; speedup vs baseline: 9.5245x; 1.0997x over previous
//
#include <hip/hip_runtime.h>

typedef __attribute__((ext_vector_type(4))) int i32x4;
typedef __attribute__((ext_vector_type(16))) int i32x16;

#define K_ELEMS 4096
#define N_DIM 4096
#define BM 256
#define BN 256
#define BKB 128            // K-bytes per tile row (i8) — R10 geometry
#define NT (K_ELEMS / BKB) // 32 K-tiles
#define HALF (128 * BKB)   // bytes per half-tile region (16384)
#define BOFF (BM * BKB)    // B region offset within a buffer (32768 bytes)

// ---------- helpers ----------

__device__ __forceinline__ void gload16(const signed char* g, signed char* l) {
  __builtin_amdgcn_global_load_lds(
      (const __attribute__((address_space(1))) void*)g,
      (__attribute__((address_space(3))) void*)l,
      16, 0, 0);
}

// swizzle v2 (R9/R10-validated: ZERO conflicts with this exact read pattern):
// 16B-slot index ^= (row&7) ^ ((row>>3)&3), rows are 128B (8 slots)
__device__ __forceinline__ i32x4 ldfrag_(const signed char* p, int row, int c16) {
  int o = row * BKB + ((c16 ^ ((row & 7) ^ ((row >> 3) & 3))) << 4);
  return *reinterpret_cast<const i32x4*>(p + o);
}

// ---------- fused prep (validated R11): rows [0,Mdim) prune+quant x; rest quant w ----------

__global__ void __launch_bounds__(256) quant_all(const float* __restrict__ x,
                                                 const float* __restrict__ w,
                                                 signed char* __restrict__ xq,
                                                 signed char* __restrict__ wq,
                                                 float* __restrict__ sx,
                                                 float* __restrict__ sw, int Mdim) {
  const int blk = blockIdx.x;
  const bool isX = blk < Mdim;
  const int row = isX ? blk : blk - Mdim;
  const float* in = isX ? x : w;
  signed char* q = isX ? xq : wq;
  float* sc = isX ? sx : sw;

  const float4* rf = reinterpret_cast<const float4*>(in + (size_t)row * K_ELEMS);
  float4 vals[4];
  float m = 0.f;
#pragma unroll
  for (int i = 0; i < 4; ++i) {
    float4 v = rf[threadIdx.x + i * 256];   // one float4 == one 2:4 group
    if (isX) {
      float vv[4] = {v.x, v.y, v.z, v.w};
      float av[4] = {fabsf(v.x), fabsf(v.y), fabsf(v.z), fabsf(v.w)};
      float o[4];
#pragma unroll
      for (int e = 0; e < 4; ++e) {
        int beats = 0;
#pragma unroll
        for (int j = 0; j < 4; ++j) {
          if (j == e) continue;
          beats += (av[j] > av[e] || (av[j] == av[e] && j < e)) ? 1 : 0;
        }
        o[e] = (beats < 2) ? vv[e] : 0.0f;
      }
      v.x = o[0]; v.y = o[1]; v.z = o[2]; v.w = o[3];
    }
    vals[i] = v;
    m = fmaxf(m, fmaxf(fmaxf(fabsf(v.x), fabsf(v.y)), fmaxf(fabsf(v.z), fabsf(v.w))));
  }
#pragma unroll
  for (int off = 32; off; off >>= 1) m = fmaxf(m, __shfl_xor(m, off));
  __shared__ float red[4];
  if ((threadIdx.x & 63) == 0) red[threadIdx.x >> 6] = m;
  __syncthreads();
  const float rm = fmaxf(fmaxf(red[0], red[1]), fmaxf(red[2], red[3]));
  const float inv = rm > 0.f ? 127.0f / rm : 0.f;
  if (threadIdx.x == 0) sc[row] = rm * (1.0f / 127.0f);
  int* qo = reinterpret_cast<int*>(q + (size_t)row * K_ELEMS);
#pragma unroll
  for (int i = 0; i < 4; ++i) {
    int q0 = __float2int_rn(vals[i].x * inv);
    int q1 = __float2int_rn(vals[i].y * inv);
    int q2 = __float2int_rn(vals[i].z * inv);
    int q3 = __float2int_rn(vals[i].w * inv);
    qo[threadIdx.x + i * 256] = (q0 & 255) | ((q1 & 255) << 8) | ((q2 & 255) << 16) | (q3 << 24);
  }
}

// ---------- 256x256 i8 GEMM: R10 base, 4 phases merged into 2 (R12->R13) ----------
// PH1: {16 ds_reads (A-mh0, B-h0, B-h1) | stage ALL 4 halves of t+1 into Ln |
//       barrier | lgkmcnt(0) | 16 MFMA Q(0,0)+Q(0,1) | barrier}
// PH2: {8 ds_reads (A-mh1) | barrier | lgkmcnt(0) | 16 MFMA Q(1,1)+Q(1,0) |
//       vmcnt(0) | barrier}
// Race ledger: Ln regions all last read at t-1 (drained by t-1's lgkmcnt(0)s +
// barriers) -> staging anywhere in Ln at t.PH1 is safe. vmcnt(0) at PH2-end
// waits loads issued ~2 phases earlier (~2500cy) -> HBM latency covered.
// Register ledger = R10 exactly (a[2][4] reused, b0/b1 live, acc 8xi32x16).

#define LD_A32(LP, MH)                                                      \
  _Pragma("unroll") for (int m_ = 0; m_ < 2; ++m_)                          \
  _Pragma("unroll") for (int ks_ = 0; ks_ < 4; ++ks_)                       \
    a[m_][ks_] = ldfrag_((LP), wrow0 + (MH)*64 + m_*32 + r32, ks_*2 + kh);

#define LD_B32(LP, NH, BV)                                                  \
  _Pragma("unroll") for (int ks_ = 0; ks_ < 4; ++ks_)                       \
    BV[ks_] = ldfrag_((LP) + BOFF, wcol0 + (NH)*32 + r32, ks_*2 + kh);

#define QUAD32(MH, NH, BV)                                                  \
  _Pragma("unroll") for (int m_ = 0; m_ < 2; ++m_)                          \
  _Pragma("unroll") for (int ks_ = 0; ks_ < 4; ++ks_)                       \
    acc[(MH)*2 + m_][NH] = __builtin_amdgcn_mfma_i32_32x32x32_i8(            \
        a[m_][ks_], BV[ks_], acc[(MH)*2 + m_][NH], 0, 0, 0);

#define STG(G, O0, O1, LP, KK)                                              \
  do { gload16((G) + (O0) + (KK), (LP) + l0);                               \
       gload16((G) + (O1) + (KK), (LP) + l1); } while (0)

__global__ void __launch_bounds__(512, 2) gemm256(const signed char* __restrict__ A,
                                                  const signed char* __restrict__ B,
                                                  const float* __restrict__ sx,
                                                  const float* __restrict__ sw,
                                                  float* __restrict__ C) {
  __shared__ signed char lds[2][2 * BM * BKB];  // [buf][ A(32768) | B(32768) ]

  const int nbn = N_DIM / BN;                 // 16
  const int cpx = gridDim.x >> 3;             // grid % 8 == 0 (bijective XCD swizzle)
  const int bid = blockIdx.x;
  const int swz = (bid & 7) * cpx + (bid >> 3);
  const int bm = swz / nbn, bn = swz % nbn;

  const int tid = threadIdx.x;
  const int lane = tid & 63;
  const int wid = tid >> 6;
  const int wr = wid >> 2;                    // 0..1: M half
  const int wc = wid & 3;                     // 0..3: N quarter
  const int r32 = lane & 31;
  const int kh = lane >> 5;                   // k 16-byte half 0..1
  const int wrow0 = wr * 128;
  const int wcol0 = wc * 64;

  // staging: 1024 x 16B chunks per half-tile; thread covers chunks tid, tid+512.
  // linear LDS dest; inverse-swizzled global source (same involution as read)
  const int c0 = tid, c1 = tid + 512;
  const int s0 = c0 ^ ((c0 >> 3) & 7) ^ ((c0 >> 6) & 3);
  const int s1 = c1 ^ ((c1 >> 3) & 7) ^ ((c1 >> 6) & 3);
  const int l0 = c0 * 16, l1 = c1 * 16;       // lds byte offsets within half
  const size_t aRow = (size_t)bm * BM, bRow = (size_t)bn * BN;
  const size_t gA00 = (aRow +       (s0 >> 3)) * K_ELEMS + (s0 & 7) * 16;
  const size_t gA01 = (aRow +       (s1 >> 3)) * K_ELEMS + (s1 & 7) * 16;
  const size_t gA10 = (aRow + 128 + (s0 >> 3)) * K_ELEMS + (s0 & 7) * 16;
  const size_t gA11 = (aRow + 128 + (s1 >> 3)) * K_ELEMS + (s1 & 7) * 16;
  const size_t gB00 = (bRow +       (s0 >> 3)) * K_ELEMS + (s0 & 7) * 16;
  const size_t gB01 = (bRow +       (s1 >> 3)) * K_ELEMS + (s1 & 7) * 16;
  const size_t gB10 = (bRow + 128 + (s0 >> 3)) * K_ELEMS + (s0 & 7) * 16;
  const size_t gB11 = (bRow + 128 + (s1 >> 3)) * K_ELEMS + (s1 & 7) * 16;

  i32x4 a[2][4], b0[4], b1[4];
  i32x16 acc[4][2] = {};

  // prologue: stage tile0 only; full drain
  STG(A, gA00, gA01, &lds[0][0], 0);
  STG(A, gA10, gA11, &lds[0][HALF], 0);
  STG(B, gB00, gB01, &lds[0][BOFF], 0);
  STG(B, gB10, gB11, &lds[0][BOFF + HALF], 0);
  asm volatile("s_waitcnt vmcnt(0)" ::: "memory");
  __builtin_amdgcn_s_barrier();

  for (int t = 0; t < NT; ++t) {
    signed char* Lc = lds[t & 1];
    signed char* Ln = lds[(t & 1) ^ 1];
    const int k1 = ((t + 1) & (NT - 1)) * BKB;  // tail wrap: staged, never read

    // PH1: reads A-mh0 (8) + B-h0 (4) + B-h1 (4); stage ALL of tile t+1;
    //      16 MFMA on quadrants (0,0) and (0,1)
    LD_A32(Lc, 0);
    LD_B32(Lc, 0, b0);
    LD_B32(Lc, 1, b1);
    STG(A, gA00, gA01, Ln, k1);
    STG(A, gA10, gA11, Ln + HALF, k1);
    STG(B, gB00, gB01, Ln + BOFF, k1);
    STG(B, gB10, gB11, Ln + BOFF + HALF, k1);
    __builtin_amdgcn_s_barrier();
    asm volatile("s_waitcnt lgkmcnt(0)" ::: "memory");
    __builtin_amdgcn_s_setprio(1);
    QUAD32(0, 0, b0);
    QUAD32(0, 1, b1);
    __builtin_amdgcn_s_setprio(0);
    __builtin_amdgcn_s_barrier();

    // PH2: reads A-mh1 (8); 16 MFMA on quadrants (1,1) and (1,0);
    //      vmcnt(0): t+1's 8 loads were issued ~2 phases ago -> covered
    LD_A32(Lc, 1);
    __builtin_amdgcn_s_barrier();
    asm volatile("s_waitcnt lgkmcnt(0)" ::: "memory");
    __builtin_amdgcn_s_setprio(1);
    QUAD32(1, 1, b1);
    QUAD32(1, 0, b0);
    __builtin_amdgcn_s_setprio(0);
    asm volatile("s_waitcnt vmcnt(0)" ::: "memory");
    __builtin_amdgcn_s_barrier();
  }

  // epilogue: dequant out = acc * sx[row] * sw[col]
  // C/D layout: col=lane&31, row=(reg&3)+8*(reg>>2)+4*(lane>>5)
  const int rb = bm * BM + wrow0;
  const int cb = bn * BN + wcol0 + r32;
#pragma unroll
  for (int mi = 0; mi < 4; ++mi)
#pragma unroll
    for (int ni = 0; ni < 2; ++ni) {
      const int col = cb + ni * 32;
      const float swc = sw[col];
#pragma unroll
      for (int reg = 0; reg < 16; ++reg) {
        const int row = rb + mi * 32 + (reg & 3) + 8 * (reg >> 2) + 4 * kh;
        C[(size_t)row * N_DIM + col] = (float)acc[mi][ni][reg] * sx[row] * swc;
      }
    }
}

// ---------- launch ----------

extern "C" void kernel_launch(void* const* d_in, const int* in_sizes, int n_in,
                              void* d_out, int out_size, void* d_ws, size_t ws_size,
                              hipStream_t stream) {
  const float* x = (const float*)d_in[0];
  const float* w = (const float*)d_in[1];
  float* out = (float*)d_out;

  const int Mdim = in_sizes[0] / K_ELEMS;      // 8192
  const int Ndim = in_sizes[1] / K_ELEMS;      // 4096

  signed char* xq = (signed char*)d_ws;                          // 32 MB
  signed char* wq = xq + (size_t)Mdim * K_ELEMS;                 // 16 MB
  float* sx = (float*)(wq + (size_t)Ndim * K_ELEMS);             // 32 KB
  float* sw = sx + Mdim;                                         // 16 KB

  quant_all<<<Mdim + Ndim, 256, 0, stream>>>(x, w, xq, wq, sx, sw, Mdim);

  const int grid = (Mdim / BM) * (N_DIM / BN);                   // 32 * 16 = 512
  gemm256<<<grid, 512, 0, stream>>>(xq, wq, sx, sw, out);
}

// Round 14
// 196.153 us; speedup vs baseline: 9.6899x; 1.0174x over previous
//
#include <hip/hip_runtime.h>

typedef __attribute__((ext_vector_type(4))) int i32x4;
typedef __attribute__((ext_vector_type(16))) int i32x16;

#define K_ELEMS 4096
#define N_DIM 4096
#define BM 256
#define BN 256
#define BKB 128            // K-bytes per tile row (i8) — R10 geometry
#define NT (K_ELEMS / BKB) // 32 K-tiles
#define HALF (128 * BKB)   // bytes per half-tile region (16384)
#define BOFF (BM * BKB)    // B region offset within a buffer (32768 bytes)

// ---------- helpers ----------

__device__ __forceinline__ void gload16(const signed char* g, signed char* l) {
  __builtin_amdgcn_global_load_lds(
      (const __attribute__((address_space(1))) void*)g,
      (__attribute__((address_space(3))) void*)l,
      16, 0, 0);
}

// swizzle v2 (R9/R10-validated: ZERO conflicts with this exact read pattern):
// 16B-slot index ^= (row&7) ^ ((row>>3)&3), rows are 128B (8 slots)
__device__ __forceinline__ i32x4 ldfrag_(const signed char* p, int row, int c16) {
  int o = row * BKB + ((c16 ^ ((row & 7) ^ ((row >> 3) & 3))) << 4);
  return *reinterpret_cast<const i32x4*>(p + o);
}

// ---------- fused prep (validated R11/R13): rows [0,Mdim) prune+quant x; rest quant w ----------

__global__ void __launch_bounds__(256) quant_all(const float* __restrict__ x,
                                                 const float* __restrict__ w,
                                                 signed char* __restrict__ xq,
                                                 signed char* __restrict__ wq,
                                                 float* __restrict__ sx,
                                                 float* __restrict__ sw, int Mdim) {
  const int blk = blockIdx.x;
  const bool isX = blk < Mdim;
  const int row = isX ? blk : blk - Mdim;
  const float* in = isX ? x : w;
  signed char* q = isX ? xq : wq;
  float* sc = isX ? sx : sw;

  const float4* rf = reinterpret_cast<const float4*>(in + (size_t)row * K_ELEMS);
  float4 vals[4];
  float m = 0.f;
#pragma unroll
  for (int i = 0; i < 4; ++i) {
    float4 v = rf[threadIdx.x + i * 256];   // one float4 == one 2:4 group
    if (isX) {
      float vv[4] = {v.x, v.y, v.z, v.w};
      float av[4] = {fabsf(v.x), fabsf(v.y), fabsf(v.z), fabsf(v.w)};
      float o[4];
#pragma unroll
      for (int e = 0; e < 4; ++e) {
        int beats = 0;
#pragma unroll
        for (int j = 0; j < 4; ++j) {
          if (j == e) continue;
          beats += (av[j] > av[e] || (av[j] == av[e] && j < e)) ? 1 : 0;
        }
        o[e] = (beats < 2) ? vv[e] : 0.0f;
      }
      v.x = o[0]; v.y = o[1]; v.z = o[2]; v.w = o[3];
    }
    vals[i] = v;
    m = fmaxf(m, fmaxf(fmaxf(fabsf(v.x), fabsf(v.y)), fmaxf(fabsf(v.z), fabsf(v.w))));
  }
#pragma unroll
  for (int off = 32; off; off >>= 1) m = fmaxf(m, __shfl_xor(m, off));
  __shared__ float red[4];
  if ((threadIdx.x & 63) == 0) red[threadIdx.x >> 6] = m;
  __syncthreads();
  const float rm = fmaxf(fmaxf(red[0], red[1]), fmaxf(red[2], red[3]));
  const float inv = rm > 0.f ? 127.0f / rm : 0.f;
  if (threadIdx.x == 0) sc[row] = rm * (1.0f / 127.0f);
  int* qo = reinterpret_cast<int*>(q + (size_t)row * K_ELEMS);
#pragma unroll
  for (int i = 0; i < 4; ++i) {
    int q0 = __float2int_rn(vals[i].x * inv);
    int q1 = __float2int_rn(vals[i].y * inv);
    int q2 = __float2int_rn(vals[i].z * inv);
    int q3 = __float2int_rn(vals[i].w * inv);
    qo[threadIdx.x + i * 256] = (q0 & 255) | ((q1 & 255) << 8) | ((q2 & 255) << 16) | (q3 << 24);
  }
}

// ---------- 256x256 i8 GEMM: R10 verbatim (best measured: 145us, MfmaUtil 42.5%) ----------
// mfma_i32_32x32x32_i8; 4-phase R2 skeleton; swizzle v2; vmcnt(2) tail;
// C/D: col=lane&31, row=(reg&3)+8*(reg>>2)+4*(lane>>5).

#define LD_A32(LP, MH)                                                      \
  _Pragma("unroll") for (int m_ = 0; m_ < 2; ++m_)                          \
  _Pragma("unroll") for (int ks_ = 0; ks_ < 4; ++ks_)                       \
    a[m_][ks_] = ldfrag_((LP), wrow0 + (MH)*64 + m_*32 + r32, ks_*2 + kh);

#define LD_B32(LP, NH, BV)                                                  \
  _Pragma("unroll") for (int ks_ = 0; ks_ < 4; ++ks_)                       \
    BV[ks_] = ldfrag_((LP) + BOFF, wcol0 + (NH)*32 + r32, ks_*2 + kh);

#define QUAD32(MH, NH, BV)                                                  \
  _Pragma("unroll") for (int m_ = 0; m_ < 2; ++m_)                          \
  _Pragma("unroll") for (int ks_ = 0; ks_ < 4; ++ks_)                       \
    acc[(MH)*2 + m_][NH] = __builtin_amdgcn_mfma_i32_32x32x32_i8(            \
        a[m_][ks_], BV[ks_], acc[(MH)*2 + m_][NH], 0, 0, 0);

#define STG(G, O0, O1, LP, KK)                                              \
  do { gload16((G) + (O0) + (KK), (LP) + l0);                               \
       gload16((G) + (O1) + (KK), (LP) + l1); } while (0)

__global__ void __launch_bounds__(512, 2) gemm256(const signed char* __restrict__ A,
                                                  const signed char* __restrict__ B,
                                                  const float* __restrict__ sx,
                                                  const float* __restrict__ sw,
                                                  float* __restrict__ C) {
  __shared__ signed char lds[2][2 * BM * BKB];  // [buf][ A(32768) | B(32768) ] bytes

  const int nbn = N_DIM / BN;                 // 16
  const int cpx = gridDim.x >> 3;             // grid % 8 == 0 (bijective XCD swizzle)
  const int bid = blockIdx.x;
  const int swz = (bid & 7) * cpx + (bid >> 3);
  const int bm = swz / nbn, bn = swz % nbn;

  const int tid = threadIdx.x;
  const int lane = tid & 63;
  const int wid = tid >> 6;
  const int wr = wid >> 2;                    // 0..1: M half
  const int wc = wid & 3;                     // 0..3: N quarter
  const int r32 = lane & 31;
  const int kh = lane >> 5;                   // k 16-byte half 0..1
  const int wrow0 = wr * 128;
  const int wcol0 = wc * 64;

  // staging: 1024 x 16B chunks per half-tile; thread covers chunks tid, tid+512.
  // linear LDS dest; inverse-swizzled global source (same involution as read)
  const int c0 = tid, c1 = tid + 512;
  const int s0 = c0 ^ ((c0 >> 3) & 7) ^ ((c0 >> 6) & 3);
  const int s1 = c1 ^ ((c1 >> 3) & 7) ^ ((c1 >> 6) & 3);
  const int l0 = c0 * 16, l1 = c1 * 16;       // lds byte offsets within half
  const size_t aRow = (size_t)bm * BM, bRow = (size_t)bn * BN;
  const size_t gA00 = (aRow +       (s0 >> 3)) * K_ELEMS + (s0 & 7) * 16;
  const size_t gA01 = (aRow +       (s1 >> 3)) * K_ELEMS + (s1 & 7) * 16;
  const size_t gA10 = (aRow + 128 + (s0 >> 3)) * K_ELEMS + (s0 & 7) * 16;
  const size_t gA11 = (aRow + 128 + (s1 >> 3)) * K_ELEMS + (s1 & 7) * 16;
  const size_t gB00 = (bRow +       (s0 >> 3)) * K_ELEMS + (s0 & 7) * 16;
  const size_t gB01 = (bRow +       (s1 >> 3)) * K_ELEMS + (s1 & 7) * 16;
  const size_t gB10 = (bRow + 128 + (s0 >> 3)) * K_ELEMS + (s0 & 7) * 16;
  const size_t gB11 = (bRow + 128 + (s1 >> 3)) * K_ELEMS + (s1 & 7) * 16;

  i32x4 a[2][4], b0[4], b1[4];
  i32x16 acc[4][2] = {};

  // prologue (R2/R10 exact): tile0 full + tile1 A-h0; vmcnt(2)
  STG(A, gA00, gA01, &lds[0][0], 0);
  STG(A, gA10, gA11, &lds[0][HALF], 0);
  STG(B, gB00, gB01, &lds[0][BOFF], 0);
  STG(B, gB10, gB11, &lds[0][BOFF + HALF], 0);
  STG(A, gA00, gA01, &lds[1][0], BKB);
  asm volatile("s_waitcnt vmcnt(2)" ::: "memory");
  __builtin_amdgcn_s_barrier();

  for (int t = 0; t < NT; ++t) {
    signed char* Lc = lds[t & 1];
    signed char* Ln = lds[(t & 1) ^ 1];
    const int k1 = ((t + 1) & (NT - 1)) * BKB;  // tail wrap: redundant, harmless
    const int k2 = ((t + 2) & (NT - 1)) * BKB;

    // P1: A[mh0] + B[nh0] reads (12); stage A-h1(t+1); quadrant (0,0)
    LD_A32(Lc, 0);
    LD_B32(Lc, 0, b0);
    STG(A, gA10, gA11, Ln + HALF, k1);
    __builtin_amdgcn_s_barrier();
    asm volatile("s_waitcnt lgkmcnt(0)" ::: "memory");
    __builtin_amdgcn_s_setprio(1);
    QUAD32(0, 0, b0);
    __builtin_amdgcn_s_setprio(0);
    __builtin_amdgcn_s_barrier();

    // P2: B[nh1] reads (4); stage B-h0(t+1); quadrant (0,1)
    LD_B32(Lc, 1, b1);
    STG(B, gB00, gB01, Ln + BOFF, k1);
    __builtin_amdgcn_s_barrier();
    asm volatile("s_waitcnt lgkmcnt(0)" ::: "memory");
    __builtin_amdgcn_s_setprio(1);
    QUAD32(0, 1, b1);
    __builtin_amdgcn_s_setprio(0);
    __builtin_amdgcn_s_barrier();

    // P3: A[mh1] reads (8); stage B-h1(t+1); quadrant (1,1)
    LD_A32(Lc, 1);
    STG(B, gB10, gB11, Ln + BOFF + HALF, k1);
    __builtin_amdgcn_s_barrier();
    asm volatile("s_waitcnt lgkmcnt(0)" ::: "memory");
    __builtin_amdgcn_s_setprio(1);
    QUAD32(1, 1, b1);
    __builtin_amdgcn_s_setprio(0);
    __builtin_amdgcn_s_barrier();

    // P4: no ds_reads (b0 live from P1); stage A-h0(t+2); quadrant (1,0); vmcnt(2)
    STG(A, gA00, gA01, Lc, k2);
    __builtin_amdgcn_s_barrier();
    __builtin_amdgcn_s_setprio(1);
    QUAD32(1, 0, b0);
    __builtin_amdgcn_s_setprio(0);
    asm volatile("s_waitcnt vmcnt(2)" ::: "memory");
    __builtin_amdgcn_s_barrier();
  }

  // epilogue: dequant out = acc * sx[row] * sw[col]
  const int rb = bm * BM + wrow0;
  const int cb = bn * BN + wcol0 + r32;
#pragma unroll
  for (int mi = 0; mi < 4; ++mi)
#pragma unroll
    for (int ni = 0; ni < 2; ++ni) {
      const int col = cb + ni * 32;
      const float swc = sw[col];
#pragma unroll
      for (int reg = 0; reg < 16; ++reg) {
        const int row = rb + mi * 32 + (reg & 3) + 8 * (reg >> 2) + 4 * kh;
        C[(size_t)row * N_DIM + col] = (float)acc[mi][ni][reg] * sx[row] * swc;
      }
    }
}

// ---------- launch ----------

extern "C" void kernel_launch(void* const* d_in, const int* in_sizes, int n_in,
                              void* d_out, int out_size, void* d_ws, size_t ws_size,
                              hipStream_t stream) {
  const float* x = (const float*)d_in[0];
  const float* w = (const float*)d_in[1];
  float* out = (float*)d_out;

  const int Mdim = in_sizes[0] / K_ELEMS;      // 8192
  const int Ndim = in_sizes[1] / K_ELEMS;      // 4096

  signed char* xq = (signed char*)d_ws;                          // 32 MB
  signed char* wq = xq + (size_t)Mdim * K_ELEMS;                 // 16 MB
  float* sx = (float*)(wq + (size_t)Ndim * K_ELEMS);             // 32 KB
  float* sw = sx + Mdim;                                         // 16 KB

  quant_all<<<Mdim + Ndim, 256, 0, stream>>>(x, w, xq, wq, sx, sw, Mdim);

  const int grid = (Mdim / BM) * (N_DIM / BN);                   // 32 * 16 = 512
  gemm256<<<grid, 512, 0, stream>>>(xq, wq, sx, sw, out);
}

// Round 15
// 196.089 us; speedup vs baseline: 9.6931x; 1.0003x over previous
//
#include <hip/hip_runtime.h>

typedef __attribute__((ext_vector_type(4))) int i32x4;
typedef __attribute__((ext_vector_type(16))) int i32x16;

#define K_ELEMS 4096
#define N_DIM 4096
#define BM 256
#define BN 256
#define BKB 128            // K-bytes per tile row (i8) — R10 geometry
#define NT (K_ELEMS / BKB) // 32 K-tiles
#define HALF (128 * BKB)   // bytes per half-tile region (16384)
#define BOFF (BM * BKB)    // B region offset within a buffer (32768 bytes)

// ---------- helpers ----------

__device__ __forceinline__ void gload16(const signed char* g, signed char* l) {
  __builtin_amdgcn_global_load_lds(
      (const __attribute__((address_space(1))) void*)g,
      (__attribute__((address_space(3))) void*)l,
      16, 0, 0);
}

// swizzle v2 (R9/R10-validated: ZERO conflicts with this exact read pattern):
// 16B-slot index ^= (row&7) ^ ((row>>3)&3), rows are 128B (8 slots)
__device__ __forceinline__ i32x4 ldfrag_(const signed char* p, int row, int c16) {
  int o = row * BKB + ((c16 ^ ((row & 7) ^ ((row >> 3) & 3))) << 4);
  return *reinterpret_cast<const i32x4*>(p + o);
}

// ---------- fused prep (validated R11/R13/R14): prune+quant x; quant w ----------

__global__ void __launch_bounds__(256) quant_all(const float* __restrict__ x,
                                                 const float* __restrict__ w,
                                                 signed char* __restrict__ xq,
                                                 signed char* __restrict__ wq,
                                                 float* __restrict__ sx,
                                                 float* __restrict__ sw, int Mdim) {
  const int blk = blockIdx.x;
  const bool isX = blk < Mdim;
  const int row = isX ? blk : blk - Mdim;
  const float* in = isX ? x : w;
  signed char* q = isX ? xq : wq;
  float* sc = isX ? sx : sw;

  const float4* rf = reinterpret_cast<const float4*>(in + (size_t)row * K_ELEMS);
  float4 vals[4];
  float m = 0.f;
#pragma unroll
  for (int i = 0; i < 4; ++i) {
    float4 v = rf[threadIdx.x + i * 256];   // one float4 == one 2:4 group
    if (isX) {
      float vv[4] = {v.x, v.y, v.z, v.w};
      float av[4] = {fabsf(v.x), fabsf(v.y), fabsf(v.z), fabsf(v.w)};
      float o[4];
#pragma unroll
      for (int e = 0; e < 4; ++e) {
        int beats = 0;
#pragma unroll
        for (int j = 0; j < 4; ++j) {
          if (j == e) continue;
          beats += (av[j] > av[e] || (av[j] == av[e] && j < e)) ? 1 : 0;
        }
        o[e] = (beats < 2) ? vv[e] : 0.0f;
      }
      v.x = o[0]; v.y = o[1]; v.z = o[2]; v.w = o[3];
    }
    vals[i] = v;
    m = fmaxf(m, fmaxf(fmaxf(fabsf(v.x), fabsf(v.y)), fmaxf(fabsf(v.z), fabsf(v.w))));
  }
#pragma unroll
  for (int off = 32; off; off >>= 1) m = fmaxf(m, __shfl_xor(m, off));
  __shared__ float red[4];
  if ((threadIdx.x & 63) == 0) red[threadIdx.x >> 6] = m;
  __syncthreads();
  const float rm = fmaxf(fmaxf(red[0], red[1]), fmaxf(red[2], red[3]));
  const float inv = rm > 0.f ? 127.0f / rm : 0.f;
  if (threadIdx.x == 0) sc[row] = rm * (1.0f / 127.0f);
  int* qo = reinterpret_cast<int*>(q + (size_t)row * K_ELEMS);
#pragma unroll
  for (int i = 0; i < 4; ++i) {
    int q0 = __float2int_rn(vals[i].x * inv);
    int q1 = __float2int_rn(vals[i].y * inv);
    int q2 = __float2int_rn(vals[i].z * inv);
    int q3 = __float2int_rn(vals[i].w * inv);
    qo[threadIdx.x + i * 256] = (q0 & 255) | ((q1 & 255) << 8) | ((q2 & 255) << 16) | (q3 << 24);
  }
}

// ---------- 256x256 i8 GEMM: R10/R14 base; R15 change = REMOVE the explicit
// lgkmcnt(0) drains before MFMA clusters. The ds_reads are plain C++ loads, so
// the compiler emits precise counted lgkmcnt per MFMA operand (m97 behavior):
// late ds_reads now complete UNDER the early MFMAs instead of serializing
// ahead of the whole cluster. WAR safety unchanged: reads complete before
// each wave's MFMAs issue, which precede the phase-end barrier, which
// precedes any overwrite of that region.

#define LD_A32(LP, MH)                                                      \
  _Pragma("unroll") for (int m_ = 0; m_ < 2; ++m_)                          \
  _Pragma("unroll") for (int ks_ = 0; ks_ < 4; ++ks_)                       \
    a[m_][ks_] = ldfrag_((LP), wrow0 + (MH)*64 + m_*32 + r32, ks_*2 + kh);

#define LD_B32(LP, NH, BV)                                                  \
  _Pragma("unroll") for (int ks_ = 0; ks_ < 4; ++ks_)                       \
    BV[ks_] = ldfrag_((LP) + BOFF, wcol0 + (NH)*32 + r32, ks_*2 + kh);

#define QUAD32(MH, NH, BV)                                                  \
  _Pragma("unroll") for (int m_ = 0; m_ < 2; ++m_)                          \
  _Pragma("unroll") for (int ks_ = 0; ks_ < 4; ++ks_)                       \
    acc[(MH)*2 + m_][NH] = __builtin_amdgcn_mfma_i32_32x32x32_i8(            \
        a[m_][ks_], BV[ks_], acc[(MH)*2 + m_][NH], 0, 0, 0);

#define STG(G, O0, O1, LP, KK)                                              \
  do { gload16((G) + (O0) + (KK), (LP) + l0);                               \
       gload16((G) + (O1) + (KK), (LP) + l1); } while (0)

__global__ void __launch_bounds__(512, 2) gemm256(const signed char* __restrict__ A,
                                                  const signed char* __restrict__ B,
                                                  const float* __restrict__ sx,
                                                  const float* __restrict__ sw,
                                                  float* __restrict__ C) {
  __shared__ signed char lds[2][2 * BM * BKB];  // [buf][ A(32768) | B(32768) ] bytes

  const int nbn = N_DIM / BN;                 // 16
  const int cpx = gridDim.x >> 3;             // grid % 8 == 0 (bijective XCD swizzle)
  const int bid = blockIdx.x;
  const int swz = (bid & 7) * cpx + (bid >> 3);
  const int bm = swz / nbn, bn = swz % nbn;

  const int tid = threadIdx.x;
  const int lane = tid & 63;
  const int wid = tid >> 6;
  const int wr = wid >> 2;                    // 0..1: M half
  const int wc = wid & 3;                     // 0..3: N quarter
  const int r32 = lane & 31;
  const int kh = lane >> 5;                   // k 16-byte half 0..1
  const int wrow0 = wr * 128;
  const int wcol0 = wc * 64;

  // staging: 1024 x 16B chunks per half-tile; thread covers chunks tid, tid+512.
  // linear LDS dest; inverse-swizzled global source (same involution as read)
  const int c0 = tid, c1 = tid + 512;
  const int s0 = c0 ^ ((c0 >> 3) & 7) ^ ((c0 >> 6) & 3);
  const int s1 = c1 ^ ((c1 >> 3) & 7) ^ ((c1 >> 6) & 3);
  const int l0 = c0 * 16, l1 = c1 * 16;       // lds byte offsets within half
  const size_t aRow = (size_t)bm * BM, bRow = (size_t)bn * BN;
  const size_t gA00 = (aRow +       (s0 >> 3)) * K_ELEMS + (s0 & 7) * 16;
  const size_t gA01 = (aRow +       (s1 >> 3)) * K_ELEMS + (s1 & 7) * 16;
  const size_t gA10 = (aRow + 128 + (s0 >> 3)) * K_ELEMS + (s0 & 7) * 16;
  const size_t gA11 = (aRow + 128 + (s1 >> 3)) * K_ELEMS + (s1 & 7) * 16;
  const size_t gB00 = (bRow +       (s0 >> 3)) * K_ELEMS + (s0 & 7) * 16;
  const size_t gB01 = (bRow +       (s1 >> 3)) * K_ELEMS + (s1 & 7) * 16;
  const size_t gB10 = (bRow + 128 + (s0 >> 3)) * K_ELEMS + (s0 & 7) * 16;
  const size_t gB11 = (bRow + 128 + (s1 >> 3)) * K_ELEMS + (s1 & 7) * 16;

  i32x4 a[2][4], b0[4], b1[4];
  i32x16 acc[4][2] = {};

  // prologue (R10 exact): tile0 full + tile1 A-h0; vmcnt(2)
  STG(A, gA00, gA01, &lds[0][0], 0);
  STG(A, gA10, gA11, &lds[0][HALF], 0);
  STG(B, gB00, gB01, &lds[0][BOFF], 0);
  STG(B, gB10, gB11, &lds[0][BOFF + HALF], 0);
  STG(A, gA00, gA01, &lds[1][0], BKB);
  asm volatile("s_waitcnt vmcnt(2)" ::: "memory");
  __builtin_amdgcn_s_barrier();

  for (int t = 0; t < NT; ++t) {
    signed char* Lc = lds[t & 1];
    signed char* Ln = lds[(t & 1) ^ 1];
    const int k1 = ((t + 1) & (NT - 1)) * BKB;  // tail wrap: redundant, harmless
    const int k2 = ((t + 2) & (NT - 1)) * BKB;

    // P1: A[mh0] + B[nh0] reads (12); stage A-h1(t+1); quadrant (0,0)
    LD_A32(Lc, 0);
    LD_B32(Lc, 0, b0);
    STG(A, gA10, gA11, Ln + HALF, k1);
    __builtin_amdgcn_s_barrier();
    __builtin_amdgcn_s_setprio(1);
    QUAD32(0, 0, b0);                 // compiler inserts counted lgkmcnt per operand
    __builtin_amdgcn_s_setprio(0);
    __builtin_amdgcn_s_barrier();

    // P2: B[nh1] reads (4); stage B-h0(t+1); quadrant (0,1)
    LD_B32(Lc, 1, b1);
    STG(B, gB00, gB01, Ln + BOFF, k1);
    __builtin_amdgcn_s_barrier();
    __builtin_amdgcn_s_setprio(1);
    QUAD32(0, 1, b1);
    __builtin_amdgcn_s_setprio(0);
    __builtin_amdgcn_s_barrier();

    // P3: A[mh1] reads (8); stage B-h1(t+1); quadrant (1,1)
    LD_A32(Lc, 1);
    STG(B, gB10, gB11, Ln + BOFF + HALF, k1);
    __builtin_amdgcn_s_barrier();
    __builtin_amdgcn_s_setprio(1);
    QUAD32(1, 1, b1);
    __builtin_amdgcn_s_setprio(0);
    __builtin_amdgcn_s_barrier();

    // P4: no ds_reads (b0 live from P1); stage A-h0(t+2); quadrant (1,0); vmcnt(2)
    STG(A, gA00, gA01, Lc, k2);
    __builtin_amdgcn_s_barrier();
    __builtin_amdgcn_s_setprio(1);
    QUAD32(1, 0, b0);
    __builtin_amdgcn_s_setprio(0);
    asm volatile("s_waitcnt vmcnt(2)" ::: "memory");
    __builtin_amdgcn_s_barrier();
  }

  // epilogue: dequant out = acc * sx[row] * sw[col]
  // C/D layout: col=lane&31, row=(reg&3)+8*(reg>>2)+4*(lane>>5)
  const int rb = bm * BM + wrow0;
  const int cb = bn * BN + wcol0 + r32;
#pragma unroll
  for (int mi = 0; mi < 4; ++mi)
#pragma unroll
    for (int ni = 0; ni < 2; ++ni) {
      const int col = cb + ni * 32;
      const float swc = sw[col];
#pragma unroll
      for (int reg = 0; reg < 16; ++reg) {
        const int row = rb + mi * 32 + (reg & 3) + 8 * (reg >> 2) + 4 * kh;
        C[(size_t)row * N_DIM + col] = (float)acc[mi][ni][reg] * sx[row] * swc;
      }
    }
}

// ---------- launch ----------

extern "C" void kernel_launch(void* const* d_in, const int* in_sizes, int n_in,
                              void* d_out, int out_size, void* d_ws, size_t ws_size,
                              hipStream_t stream) {
  const float* x = (const float*)d_in[0];
  const float* w = (const float*)d_in[1];
  float* out = (float*)d_out;

  const int Mdim = in_sizes[0] / K_ELEMS;      // 8192
  const int Ndim = in_sizes[1] / K_ELEMS;      // 4096

  signed char* xq = (signed char*)d_ws;                          // 32 MB
  signed char* wq = xq + (size_t)Mdim * K_ELEMS;                 // 16 MB
  float* sx = (float*)(wq + (size_t)Ndim * K_ELEMS);             // 32 KB
  float* sw = sx + Mdim;                                         // 16 KB

  quant_all<<<Mdim + Ndim, 256, 0, stream>>>(x, w, xq, wq, sx, sw, Mdim);

  const int grid = (Mdim / BM) * (N_DIM / BN);                   // 32 * 16 = 512
  gemm256<<<grid, 512, 0, stream>>>(xq, wq, sx, sw, out);
}